// Round 1
// baseline (1093.835 us; speedup 1.0000x reference)
//
#include <hip/hip_runtime.h>
#include <hip/hip_bf16.h>

// Problem constants
#define M_DIM 16384   // 8*2048
#define N_DIM 4096    // OUT_FEATURES
#define K_DIM 4096    // IN_FEATURES

typedef __attribute__((ext_vector_type(8))) short short8_t;
typedef __attribute__((ext_vector_type(4))) float float4_t;

__device__ __forceinline__ short f2bf(float f) {
    union { __hip_bfloat16 b; short s; } u;
    u.b = __float2bfloat16(f);
    return u.s;
}

// ---------------------------------------------------------------------------
// Kernel 1: dequantize packed 4-bit weights -> bf16 [N][K] (K-major)
// weight_data: [4096][2048] int32 (each value 0..255 = one packed byte)
// scale:       [4096][32] f32 (per-128-element group)
// lut:         [256][2] f32  (hi, lo)
// ---------------------------------------------------------------------------
__global__ __launch_bounds__(256) void dequant_w(const int* __restrict__ wd,
                                                 const float* __restrict__ scale,
                                                 const float* __restrict__ lut,
                                                 short* __restrict__ Wq) {
    int t = blockIdx.x * 256 + threadIdx.x;       // 2,097,152 threads total
    int row = t >> 9;                             // / 512  (512 threads per row)
    int cb  = t & 511;                            // 4-byte chunk index within row
    const int4 w4 = *(const int4*)&wd[(size_t)row * 2048 + cb * 4];
    // elements 8*cb .. 8*cb+7 -> group = (8*cb)/128 = cb/16 (constant over chunk)
    const float s = scale[row * 32 + (cb >> 4)];
    int idx[4] = {w4.x, w4.y, w4.z, w4.w};
    short8_t v;
#pragma unroll
    for (int j = 0; j < 4; ++j) {
        float hi = lut[idx[j] * 2 + 0] * s;
        float lo = lut[idx[j] * 2 + 1] * s;
        v[2 * j + 0] = f2bf(hi);
        v[2 * j + 1] = f2bf(lo);
    }
    *(short8_t*)&Wq[(size_t)row * K_DIM + cb * 8] = v;
}

// ---------------------------------------------------------------------------
// Kernel 2: x f32 -> bf16 (vectorized 8/thread)
// ---------------------------------------------------------------------------
__global__ __launch_bounds__(256) void conv_x(const float* __restrict__ x,
                                              short* __restrict__ xb) {
    size_t t = (size_t)blockIdx.x * 256 + threadIdx.x;  // 8,388,608 threads
    const float4 a = *(const float4*)(x + t * 8);
    const float4 b = *(const float4*)(x + t * 8 + 4);
    short8_t v;
    v[0] = f2bf(a.x); v[1] = f2bf(a.y); v[2] = f2bf(a.z); v[3] = f2bf(a.w);
    v[4] = f2bf(b.x); v[5] = f2bf(b.y); v[6] = f2bf(b.z); v[7] = f2bf(b.w);
    *(short8_t*)(xb + t * 8) = v;
}

// ---------------------------------------------------------------------------
// Kernel 3: bf16 GEMM  C[M][N] = A[M][K] * B[N][K]^T   (both K-major)
// m97 structure: 128x128 tile, BK=32, 4 waves (2x2 of 64x64),
// global_load_lds width-16 staging, 16x16x32 bf16 MFMA.
// Template AF32: if true, A is fp32 and converted to bf16 during staging.
// ---------------------------------------------------------------------------
template <bool AF32>
__global__ __launch_bounds__(256) void gemm_bf16(const void* __restrict__ Av,
                                                 const short* __restrict__ B,
                                                 float* __restrict__ C) {
    __shared__ short Al[128 * 32];
    __shared__ short Bl[128 * 32];

    const int bid = blockIdx.x;
    const int bm = bid >> 5;   // 128 m-blocks
    const int bn = bid & 31;   // 32 n-blocks
    const int tid = threadIdx.x;
    const int lane = tid & 63;
    const int w = tid >> 6;
    const int wr = w >> 1, wc = w & 1;

    const int lr = lane & 15;          // fragment row/col within 16
    const int lk = (lane >> 4) << 3;   // k-offset 0/8/16/24

    float4_t acc[4][4] = {};

    for (int k0 = 0; k0 < K_DIM; k0 += 32) {
        __syncthreads();   // previous compute done before LDS overwrite
        if constexpr (!AF32) {
            const short* A = (const short*)Av;
#pragma unroll
            for (int i = 0; i < 4; ++i) {
                int f = i * 4096 + tid * 16;        // byte offset in 16 KB tile
                int row = f >> 6, colb = f & 63;    // 64 B per row (32 bf16)
                const char* ga = (const char*)A +
                    ((size_t)(bm * 128 + row) * K_DIM + k0) * 2 + colb;
                __builtin_amdgcn_global_load_lds(
                    (const __attribute__((address_space(1))) void*)ga,
                    (__attribute__((address_space(3))) void*)((char*)Al + f), 16, 0, 0);
            }
        } else {
            const float* A = (const float*)Av;
#pragma unroll
            for (int i = 0; i < 2; ++i) {
                int e = i * 2048 + tid * 8;         // element index in 128x32 tile
                int row = e >> 5, col = e & 31;
                const float* gp = A + (size_t)(bm * 128 + row) * K_DIM + k0 + col;
                float4 fa = *(const float4*)gp;
                float4 fb = *(const float4*)(gp + 4);
                short8_t v;
                v[0] = f2bf(fa.x); v[1] = f2bf(fa.y); v[2] = f2bf(fa.z); v[3] = f2bf(fa.w);
                v[4] = f2bf(fb.x); v[5] = f2bf(fb.y); v[6] = f2bf(fb.z); v[7] = f2bf(fb.w);
                *(short8_t*)&Al[e] = v;
            }
        }
#pragma unroll
        for (int i = 0; i < 4; ++i) {
            int f = i * 4096 + tid * 16;
            int row = f >> 6, colb = f & 63;
            const char* gb = (const char*)B +
                ((size_t)(bn * 128 + row) * K_DIM + k0) * 2 + colb;
            __builtin_amdgcn_global_load_lds(
                (const __attribute__((address_space(1))) void*)gb,
                (__attribute__((address_space(3))) void*)((char*)Bl + f), 16, 0, 0);
        }
        __syncthreads();   // drains vmcnt (global_load_lds) + lgkm

        short8_t af[4], bf[4];
#pragma unroll
        for (int mi = 0; mi < 4; ++mi)
            af[mi] = *(const short8_t*)&Al[(wr * 64 + mi * 16 + lr) * 32 + lk];
#pragma unroll
        for (int ni = 0; ni < 4; ++ni)
            bf[ni] = *(const short8_t*)&Bl[(wc * 64 + ni * 16 + lr) * 32 + lk];
#pragma unroll
        for (int mi = 0; mi < 4; ++mi)
#pragma unroll
            for (int ni = 0; ni < 4; ++ni)
                acc[mi][ni] = __builtin_amdgcn_mfma_f32_16x16x32_bf16(
                    af[mi], bf[ni], acc[mi][ni], 0, 0, 0);
    }

    // Epilogue: D mapping col = lane&15, row = (lane>>4)*4 + r  (m89-verified)
    const int orow0 = bm * 128 + wr * 64;
    const int ocol0 = bn * 128 + wc * 64 + (lane & 15);
#pragma unroll
    for (int mi = 0; mi < 4; ++mi) {
#pragma unroll
        for (int r = 0; r < 4; ++r) {
            int row = orow0 + mi * 16 + ((lane >> 4) << 2) + r;
            float* cp = C + (size_t)row * N_DIM + ocol0;
#pragma unroll
            for (int ni = 0; ni < 4; ++ni)
                cp[ni * 16] = acc[mi][ni][r];
        }
    }
}

// ---------------------------------------------------------------------------
extern "C" void kernel_launch(void* const* d_in, const int* in_sizes, int n_in,
                              void* d_out, int out_size, void* d_ws, size_t ws_size,
                              hipStream_t stream) {
    const float* x     = (const float*)d_in[0];
    const int*   wd    = (const int*)d_in[1];
    const float* scale = (const float*)d_in[2];
    const float* lut   = (const float*)d_in[3];
    float* out = (float*)d_out;

    const size_t wq_bytes = (size_t)N_DIM * K_DIM * 2;           // 32 MB
    const size_t xb_bytes = (size_t)M_DIM * K_DIM * 2;           // 128 MB
    short* Wq = (short*)d_ws;
    short* xb = (short*)((char*)d_ws + wq_bytes);
    const bool have_xb = ws_size >= wq_bytes + xb_bytes;

    // 1) dequantize weights -> bf16 [N][K]
    dequant_w<<<8192, 256, 0, stream>>>(wd, scale, lut, Wq);

    const int gemm_grid = (M_DIM / 128) * (N_DIM / 128);  // 4096 blocks

    if (have_xb) {
        // 2) x -> bf16
        conv_x<<<32768, 256, 0, stream>>>(x, xb);
        // 3) GEMM (bf16 A)
        gemm_bf16<false><<<gemm_grid, 256, 0, stream>>>((const void*)xb, Wq, out);
    } else {
        // fallback: stage fp32 A with on-the-fly conversion
        gemm_bf16<true><<<gemm_grid, 256, 0, stream>>>((const void*)x, Wq, out);
    }
}

// Round 2
// 992.661 us; speedup vs baseline: 1.1019x; 1.1019x over previous
//
#include <hip/hip_runtime.h>
#include <hip/hip_bf16.h>

// Problem constants
#define M_DIM 16384   // 8*2048
#define N_DIM 4096    // OUT_FEATURES
#define K_DIM 4096    // IN_FEATURES

typedef __attribute__((ext_vector_type(8))) short short8_t;
typedef __attribute__((ext_vector_type(4))) float float4_t;

__device__ __forceinline__ short f2bf(float f) {
    union { __hip_bfloat16 b; short s; } u;
    u.b = __float2bfloat16(f);
    return u.s;
}

// ---------------------------------------------------------------------------
// Kernel 1: dequantize packed 4-bit weights -> bf16 [N][K] (K-major)
// ---------------------------------------------------------------------------
__global__ __launch_bounds__(256) void dequant_w(const int* __restrict__ wd,
                                                 const float* __restrict__ scale,
                                                 const float* __restrict__ lut,
                                                 short* __restrict__ Wq) {
    int t = blockIdx.x * 256 + threadIdx.x;       // 2,097,152 threads total
    int row = t >> 9;                             // 512 threads per row
    int cb  = t & 511;                            // 4-byte chunk index within row
    const int4 w4 = *(const int4*)&wd[(size_t)row * 2048 + cb * 4];
    const float s = scale[row * 32 + (cb >> 4)];  // group = (8*cb)/128 = cb/16
    int idx[4] = {w4.x, w4.y, w4.z, w4.w};
    short8_t v;
#pragma unroll
    for (int j = 0; j < 4; ++j) {
        v[2 * j + 0] = f2bf(lut[idx[j] * 2 + 0] * s);
        v[2 * j + 1] = f2bf(lut[idx[j] * 2 + 1] * s);
    }
    *(short8_t*)&Wq[(size_t)row * K_DIM + cb * 8] = v;
}

// ---------------------------------------------------------------------------
// Kernel 2: x f32 -> bf16 (vectorized 8/thread)
// ---------------------------------------------------------------------------
__global__ __launch_bounds__(256) void conv_x(const float* __restrict__ x,
                                              short* __restrict__ xb) {
    size_t t = (size_t)blockIdx.x * 256 + threadIdx.x;  // 8,388,608 threads
    const float4 a = *(const float4*)(x + t * 8);
    const float4 b = *(const float4*)(x + t * 8 + 4);
    short8_t v;
    v[0] = f2bf(a.x); v[1] = f2bf(a.y); v[2] = f2bf(a.z); v[3] = f2bf(a.w);
    v[4] = f2bf(b.x); v[5] = f2bf(b.y); v[6] = f2bf(b.z); v[7] = f2bf(b.w);
    *(short8_t*)(xb + t * 8) = v;
}

// ---------------------------------------------------------------------------
// Kernel 3: bf16 GEMM  C[M][N] = A[M][K] * B[N][K]^T   (both K-major)
// m97 structure: 128x128 tile, BK=32, 4 waves (2x2 of 64x64),
// global_load_lds width-16 staging, 16x16x32 bf16 MFMA.
// Tile = 128 rows x 32 bf16 = 8192 bytes = 2 x (256 threads x 16 B).
// ---------------------------------------------------------------------------
template <bool AF32>
__global__ __launch_bounds__(256) void gemm_bf16(const void* __restrict__ Av,
                                                 const short* __restrict__ B,
                                                 float* __restrict__ C) {
    __shared__ short Al[128 * 32];   // 8 KB
    __shared__ short Bl[128 * 32];   // 8 KB

    // T1: XCD-chunked bijective swizzle (grid 4096 = 8 XCDs x 512)
    const int bid0 = blockIdx.x;
    const int bid = (bid0 & 7) * 512 + (bid0 >> 3);
    const int bm = bid >> 5;   // 128 m-blocks (16 per XCD chunk)
    const int bn = bid & 31;   // 32 n-blocks (fastest: 32 blocks share A panel)
    const int tid = threadIdx.x;
    const int lane = tid & 63;
    const int w = tid >> 6;
    const int wr = w >> 1, wc = w & 1;

    const int lr = lane & 15;          // fragment row within 16
    const int lk = (lane >> 4) << 3;   // k-offset 0/8/16/24 (elements)

    float4_t acc[4][4] = {};

    for (int k0 = 0; k0 < K_DIM; k0 += 32) {
        __syncthreads();   // previous compute done before LDS overwrite
        if constexpr (!AF32) {
            const short* A = (const short*)Av;
#pragma unroll
            for (int i = 0; i < 2; ++i) {
                int f = i * 4096 + tid * 16;        // byte offset in 8 KB tile
                int row = f >> 6, colb = f & 63;    // 64 B per row (32 bf16)
                const char* ga = (const char*)A +
                    ((size_t)(bm * 128 + row) * K_DIM + k0) * 2 + colb;
                __builtin_amdgcn_global_load_lds(
                    (const __attribute__((address_space(1))) void*)ga,
                    (__attribute__((address_space(3))) void*)((char*)Al + f), 16, 0, 0);
            }
        } else {
            const float* A = (const float*)Av;
#pragma unroll
            for (int i = 0; i < 2; ++i) {
                int e = i * 2048 + tid * 8;         // element index in 128x32 tile
                int row = e >> 5, col = e & 31;
                const float* gp = A + (size_t)(bm * 128 + row) * K_DIM + k0 + col;
                float4 fa = *(const float4*)gp;
                float4 fb = *(const float4*)(gp + 4);
                short8_t v;
                v[0] = f2bf(fa.x); v[1] = f2bf(fa.y); v[2] = f2bf(fa.z); v[3] = f2bf(fa.w);
                v[4] = f2bf(fb.x); v[5] = f2bf(fb.y); v[6] = f2bf(fb.z); v[7] = f2bf(fb.w);
                *(short8_t*)&Al[e] = v;
            }
        }
#pragma unroll
        for (int i = 0; i < 2; ++i) {
            int f = i * 4096 + tid * 16;
            int row = f >> 6, colb = f & 63;
            const char* gb = (const char*)B +
                ((size_t)(bn * 128 + row) * K_DIM + k0) * 2 + colb;
            __builtin_amdgcn_global_load_lds(
                (const __attribute__((address_space(1))) void*)gb,
                (__attribute__((address_space(3))) void*)((char*)Bl + f), 16, 0, 0);
        }
        __syncthreads();   // drains vmcnt (global_load_lds) + lgkm

        short8_t af[4], bf[4];
#pragma unroll
        for (int mi = 0; mi < 4; ++mi)
            af[mi] = *(const short8_t*)&Al[(wr * 64 + mi * 16 + lr) * 32 + lk];
#pragma unroll
        for (int ni = 0; ni < 4; ++ni)
            bf[ni] = *(const short8_t*)&Bl[(wc * 64 + ni * 16 + lr) * 32 + lk];
#pragma unroll
        for (int mi = 0; mi < 4; ++mi)
#pragma unroll
            for (int ni = 0; ni < 4; ++ni)
                acc[mi][ni] = __builtin_amdgcn_mfma_f32_16x16x32_bf16(
                    af[mi], bf[ni], acc[mi][ni], 0, 0, 0);
    }

    // Epilogue: D mapping col = lane&15, row = (lane>>4)*4 + r  (m89-verified)
    const int orow0 = bm * 128 + wr * 64;
    const int ocol0 = bn * 128 + wc * 64 + (lane & 15);
#pragma unroll
    for (int mi = 0; mi < 4; ++mi) {
#pragma unroll
        for (int r = 0; r < 4; ++r) {
            int row = orow0 + mi * 16 + ((lane >> 4) << 2) + r;
            float* cp = C + (size_t)row * N_DIM + ocol0;
#pragma unroll
            for (int ni = 0; ni < 4; ++ni)
                cp[ni * 16] = acc[mi][ni][r];
        }
    }
}

// ---------------------------------------------------------------------------
extern "C" void kernel_launch(void* const* d_in, const int* in_sizes, int n_in,
                              void* d_out, int out_size, void* d_ws, size_t ws_size,
                              hipStream_t stream) {
    const float* x     = (const float*)d_in[0];
    const int*   wd    = (const int*)d_in[1];
    const float* scale = (const float*)d_in[2];
    const float* lut   = (const float*)d_in[3];
    float* out = (float*)d_out;

    const size_t wq_bytes = (size_t)N_DIM * K_DIM * 2;           // 32 MB
    const size_t xb_bytes = (size_t)M_DIM * K_DIM * 2;           // 128 MB
    short* Wq = (short*)d_ws;
    short* xb = (short*)((char*)d_ws + wq_bytes);
    const bool have_xb = ws_size >= wq_bytes + xb_bytes;

    // 1) dequantize weights -> bf16 [N][K]
    dequant_w<<<8192, 256, 0, stream>>>(wd, scale, lut, Wq);

    const int gemm_grid = (M_DIM / 128) * (N_DIM / 128);  // 4096 blocks

    if (have_xb) {
        // 2) x -> bf16
        conv_x<<<32768, 256, 0, stream>>>(x, xb);
        // 3) GEMM (bf16 A)
        gemm_bf16<false><<<gemm_grid, 256, 0, stream>>>((const void*)xb, Wq, out);
    } else {
        // fallback: stage fp32 A with on-the-fly conversion
        gemm_bf16<true><<<gemm_grid, 256, 0, stream>>>((const void*)x, Wq, out);
    }
}

// Round 3
// 575.881 us; speedup vs baseline: 1.8994x; 1.7237x over previous
//
#include <hip/hip_runtime.h>
#include <hip/hip_bf16.h>

// Problem constants
#define M_DIM 16384   // 8*2048
#define N_DIM 4096    // OUT_FEATURES
#define K_DIM 4096    // IN_FEATURES

typedef __attribute__((ext_vector_type(8))) short short8_t;
typedef __attribute__((ext_vector_type(4))) float float4_t;

__device__ __forceinline__ short f2bf(float f) {
    union { __hip_bfloat16 b; short s; } u;
    u.b = __float2bfloat16(f);
    return u.s;
}

// ---------------------------------------------------------------------------
// Kernel 1: dequantize packed 4-bit weights -> bf16 [N][K] (K-major)
// ---------------------------------------------------------------------------
__global__ __launch_bounds__(256) void dequant_w(const int* __restrict__ wd,
                                                 const float* __restrict__ scale,
                                                 const float* __restrict__ lut,
                                                 short* __restrict__ Wq) {
    int t = blockIdx.x * 256 + threadIdx.x;       // 2,097,152 threads total
    int row = t >> 9;                             // 512 threads per row
    int cb  = t & 511;                            // 4-byte chunk index within row
    const int4 w4 = *(const int4*)&wd[(size_t)row * 2048 + cb * 4];
    const float s = scale[row * 32 + (cb >> 4)];  // group = (8*cb)/128 = cb/16
    int idx[4] = {w4.x, w4.y, w4.z, w4.w};
    short8_t v;
#pragma unroll
    for (int j = 0; j < 4; ++j) {
        v[2 * j + 0] = f2bf(lut[idx[j] * 2 + 0] * s);
        v[2 * j + 1] = f2bf(lut[idx[j] * 2 + 1] * s);
    }
    *(short8_t*)&Wq[(size_t)row * K_DIM + cb * 8] = v;
}

// ---------------------------------------------------------------------------
// Kernel 2: x f32 -> bf16 (vectorized 8/thread)
// ---------------------------------------------------------------------------
__global__ __launch_bounds__(256) void conv_x(const float* __restrict__ x,
                                              short* __restrict__ xb) {
    size_t t = (size_t)blockIdx.x * 256 + threadIdx.x;  // 8,388,608 threads
    const float4 a = *(const float4*)(x + t * 8);
    const float4 b = *(const float4*)(x + t * 8 + 4);
    short8_t v;
    v[0] = f2bf(a.x); v[1] = f2bf(a.y); v[2] = f2bf(a.z); v[3] = f2bf(a.w);
    v[4] = f2bf(b.x); v[5] = f2bf(b.y); v[6] = f2bf(b.z); v[7] = f2bf(b.w);
    *(short8_t*)(xb + t * 8) = v;
}

// ---------------------------------------------------------------------------
// Kernel 3: 256x256 8-phase bf16 GEMM (T1+T2+T3+T4+T5)
//   C[M][N] = A[M][K] * B[N][K]^T, both K-major bf16.
//   512 threads = 8 waves (2 wr x 4 wc); per-wave output 128x64.
//   LDS 128 KiB: A[2 buf][2 half][2 kk][128 r][32 c], B same at +64 KiB.
//   st_16x32 swizzle: byte ^= ((byte>>9)&1)<<5  (lane-constant: bit = lr&8).
//   Staging: 1 half-tile (2 x global_load_lds w16) per phase, freed-half
//   order {Ah0, Bh1, Ah1, Bh0}; vmcnt(4) at phases 4/8 only.
// ---------------------------------------------------------------------------
#define LOADA(MH, BUF) \
  _Pragma("unroll") for (int q = 0; q < 4; ++q) { \
    afr[q][0] = *(const short8_t*)(smem + ABASE + (BUF) + ((MH)*4+q)*1024); \
    afr[q][1] = *(const short8_t*)(smem + ABASE + (BUF) + 8192 + ((MH)*4+q)*1024); }

#define LOADB(NH, BUF) \
  _Pragma("unroll") for (int q = 0; q < 2; ++q) { \
    bfr[q][0] = *(const short8_t*)(smem + BBASE + (BUF) + ((NH)*2+q)*1024); \
    bfr[q][1] = *(const short8_t*)(smem + BBASE + (BUF) + 8192 + ((NH)*2+q)*1024); }

#define MFMAQ(MH, NH) \
  _Pragma("unroll") for (int q = 0; q < 4; ++q) \
  _Pragma("unroll") for (int p = 0; p < 2; ++p) { \
    acc[(MH)*4+q][(NH)*2+p] = __builtin_amdgcn_mfma_f32_16x16x32_bf16(afr[q][0], bfr[p][0], acc[(MH)*4+q][(NH)*2+p], 0, 0, 0); \
    acc[(MH)*4+q][(NH)*2+p] = __builtin_amdgcn_mfma_f32_16x16x32_bf16(afr[q][1], bfr[p][1], acc[(MH)*4+q][(NH)*2+p], 0, 0, 0); }

#define PH(LOADS, MH, NH, SSLOT, WAITV) \
    LOADS \
    { int s_ = (SSLOT); if (s_ >= 8 && s_ < 256) STAGE(s_); } \
    __builtin_amdgcn_s_barrier(); \
    asm volatile("s_waitcnt lgkmcnt(0)" ::: "memory"); \
    __builtin_amdgcn_s_setprio(1); \
    MFMAQ(MH, NH); \
    __builtin_amdgcn_s_setprio(0); \
    WAITV \
    __builtin_amdgcn_s_barrier();

__global__ __launch_bounds__(512, 2) void gemm8(const short* __restrict__ A,
                                                const short* __restrict__ B,
                                                float* __restrict__ C) {
    __shared__ __align__(16) char smem[131072];
    const int tid = threadIdx.x;
    const int lane = tid & 63;
    const int wid = tid >> 6;
    const int wr = wid >> 2, wc = wid & 3;
    const int lr = lane & 15;
    const int lk2 = ((lane >> 4) << 3) * 2;          // frag col byte {0,16,32,48}
    const int swz5 = ((lr >> 3) & 1) << 5;

    // T1: XCD-chunked bijective swizzle (grid 1024 = 8 XCDs x 128)
    int bid = ((blockIdx.x & 7) << 7) + (blockIdx.x >> 3);
    const int bm = bid >> 4, bn = bid & 15;          // 64 x 16 tiles

    const char* Abytes = (const char*)A;
    const char* Bbytes = (const char*)B;

    // lane-constant LDS read bases (byte offsets); swizzle folded in
    const int ABASE = wr * 16384 + lr * 64 + (lk2 ^ swz5);
    const int BBASE = 65536 + (wc >> 1) * 16384 + (wc & 1) * 4096 + lr * 64 + (lk2 ^ swz5);

    // staging per-thread constants: slot i covers kk=i; same row/colswz both
    const int f0 = tid * 16;
    const int rr0 = tid >> 2;                        // LDS row 0..127
    const int cs0 = (f0 & 63) ^ (((f0 >> 9) & 1) << 5);  // inverse-swz src col byte

    float4_t acc[8][4] = {};
    short8_t afr[4][2], bfr[2][2];

    auto STAGE = [&](int s) {
        const int kt = s >> 2, idx = s & 3;          // idx: 0 Ah0, 1 Bh1, 2 Ah1, 3 Bh0
        const int isB = idx & 1;
        const int half = ((idx + 1) >> 1) & 1;
        const char* gb = isB ? Bbytes : Abytes;
        const int rb = ((isB ? bn : bm) << 8) + (half << 7) + rr0;
        const char* src = gb + ((size_t)rb * K_DIM + (size_t)kt * 64) * 2 + cs0;
        char* dst = smem + (isB << 16) + ((kt & 1) << 15) + (half << 14) + f0;
        __builtin_amdgcn_global_load_lds((const __attribute__((address_space(1))) void*)src,
            (__attribute__((address_space(3))) void*)dst, 16, 0, 0);
        __builtin_amdgcn_global_load_lds((const __attribute__((address_space(1))) void*)(src + 64),
            (__attribute__((address_space(3))) void*)(dst + 8192), 16, 0, 0);
    };

    // prologue: K-tiles 0 (buf0) and 1 (buf1) = stages s=0..7
#pragma unroll
    for (int s = 0; s < 8; ++s) STAGE(s);
    asm volatile("s_waitcnt vmcnt(8)" ::: "memory");  // buf0 landed
    __builtin_amdgcn_s_barrier();

#pragma unroll 1
    for (int t = 0; t < 32; ++t) {
        const int sb = t * 8;
        // K-tile 2t from buf0: quadrants (0,0),(0,1),(1,1),(1,0)
        PH(LOADA(0,0) LOADB(0,0), 0, 0, sb + 6, )
        PH(LOADB(1,0),            0, 1, sb + 7, )
        PH(LOADA(1,0),            1, 1, sb + 8, )
        if (t < 31) {
            PH(LOADB(0,0), 1, 0, sb + 9, asm volatile("s_waitcnt vmcnt(4)" ::: "memory");)
        } else {
            PH(LOADB(0,0), 1, 0, sb + 9, asm volatile("s_waitcnt vmcnt(0)" ::: "memory");)
        }
        // K-tile 2t+1 from buf1
        PH(LOADA(0,32768) LOADB(0,32768), 0, 0, sb + 10, )
        PH(LOADB(1,32768),                0, 1, sb + 11, )
        PH(LOADA(1,32768),                1, 1, sb + 12, )
        PH(LOADB(0,32768),                1, 0, sb + 13, asm volatile("s_waitcnt vmcnt(4)" ::: "memory");)
    }

    // Epilogue: D mapping col = lane&15, row = (lane>>4)*4 + r (m89-verified)
    const int orow0 = bm * 256 + wr * 128;
    const int ocol0 = bn * 256 + wc * 64 + lr;
    const int rsub = (lane >> 4) << 2;
#pragma unroll
    for (int mi = 0; mi < 8; ++mi) {
#pragma unroll
        for (int r = 0; r < 4; ++r) {
            int row = orow0 + mi * 16 + rsub + r;
            float* cp = C + (size_t)row * N_DIM + ocol0;
#pragma unroll
            for (int ni = 0; ni < 4; ++ni)
                cp[ni * 16] = acc[mi][ni][r];
        }
    }
}

// ---------------------------------------------------------------------------
// Fallback GEMM (fp32 A staged with conversion) — m97 structure, only used
// if workspace is too small for the bf16 x-copy.
// ---------------------------------------------------------------------------
__global__ __launch_bounds__(256) void gemm_fb(const float* __restrict__ A,
                                               const short* __restrict__ B,
                                               float* __restrict__ C) {
    __shared__ short Al[128 * 32];
    __shared__ short Bl[128 * 32];
    const int bid0 = blockIdx.x;
    const int bid = (bid0 & 7) * 512 + (bid0 >> 3);
    const int bm = bid >> 5, bn = bid & 31;
    const int tid = threadIdx.x;
    const int lane = tid & 63;
    const int w = tid >> 6;
    const int wr = w >> 1, wc = w & 1;
    const int lr = lane & 15;
    const int lk = (lane >> 4) << 3;
    float4_t acc[4][4] = {};
    for (int k0 = 0; k0 < K_DIM; k0 += 32) {
        __syncthreads();
#pragma unroll
        for (int i = 0; i < 2; ++i) {
            int e = i * 2048 + tid * 8;
            int row = e >> 5, col = e & 31;
            const float* gp = A + (size_t)(bm * 128 + row) * K_DIM + k0 + col;
            float4 fa = *(const float4*)gp;
            float4 fb = *(const float4*)(gp + 4);
            short8_t v;
            v[0] = f2bf(fa.x); v[1] = f2bf(fa.y); v[2] = f2bf(fa.z); v[3] = f2bf(fa.w);
            v[4] = f2bf(fb.x); v[5] = f2bf(fb.y); v[6] = f2bf(fb.z); v[7] = f2bf(fb.w);
            *(short8_t*)&Al[e] = v;
        }
#pragma unroll
        for (int i = 0; i < 2; ++i) {
            int f = i * 4096 + tid * 16;
            int row = f >> 6, colb = f & 63;
            const char* gb = (const char*)B + ((size_t)(bn * 128 + row) * K_DIM + k0) * 2 + colb;
            __builtin_amdgcn_global_load_lds(
                (const __attribute__((address_space(1))) void*)gb,
                (__attribute__((address_space(3))) void*)((char*)Bl + f), 16, 0, 0);
        }
        __syncthreads();
        short8_t af[4], bf[4];
#pragma unroll
        for (int mi = 0; mi < 4; ++mi)
            af[mi] = *(const short8_t*)&Al[(wr * 64 + mi * 16 + lr) * 32 + lk];
#pragma unroll
        for (int ni = 0; ni < 4; ++ni)
            bf[ni] = *(const short8_t*)&Bl[(wc * 64 + ni * 16 + lr) * 32 + lk];
#pragma unroll
        for (int mi = 0; mi < 4; ++mi)
#pragma unroll
            for (int ni = 0; ni < 4; ++ni)
                acc[mi][ni] = __builtin_amdgcn_mfma_f32_16x16x32_bf16(af[mi], bf[ni], acc[mi][ni], 0, 0, 0);
    }
    const int orow0 = bm * 128 + wr * 64;
    const int ocol0 = bn * 128 + wc * 64 + (lane & 15);
#pragma unroll
    for (int mi = 0; mi < 4; ++mi)
#pragma unroll
        for (int r = 0; r < 4; ++r) {
            int row = orow0 + mi * 16 + ((lane >> 4) << 2) + r;
            float* cp = C + (size_t)row * N_DIM + ocol0;
#pragma unroll
            for (int ni = 0; ni < 4; ++ni)
                cp[ni * 16] = acc[mi][ni][r];
        }
}

// ---------------------------------------------------------------------------
extern "C" void kernel_launch(void* const* d_in, const int* in_sizes, int n_in,
                              void* d_out, int out_size, void* d_ws, size_t ws_size,
                              hipStream_t stream) {
    const float* x     = (const float*)d_in[0];
    const int*   wd    = (const int*)d_in[1];
    const float* scale = (const float*)d_in[2];
    const float* lut   = (const float*)d_in[3];
    float* out = (float*)d_out;

    const size_t wq_bytes = (size_t)N_DIM * K_DIM * 2;   // 32 MB
    const size_t xb_bytes = (size_t)M_DIM * K_DIM * 2;   // 128 MB
    short* Wq = (short*)d_ws;
    short* xb = (short*)((char*)d_ws + wq_bytes);
    const bool have_xb = ws_size >= wq_bytes + xb_bytes;

    dequant_w<<<8192, 256, 0, stream>>>(wd, scale, lut, Wq);

    if (have_xb) {
        conv_x<<<32768, 256, 0, stream>>>(x, xb);
        gemm8<<<(M_DIM / 256) * (N_DIM / 256), 512, 0, stream>>>(xb, Wq, out);
    } else {
        gemm_fb<<<(M_DIM / 128) * (N_DIM / 128), 256, 0, stream>>>(x, Wq, out);
    }
}

// Round 5
// 564.859 us; speedup vs baseline: 1.9365x; 1.0195x over previous
//
#include <hip/hip_runtime.h>
#include <hip/hip_bf16.h>

// Problem constants
#define M_DIM 16384   // 8*2048
#define N_DIM 4096    // OUT_FEATURES
#define K_DIM 4096    // IN_FEATURES

typedef __attribute__((ext_vector_type(8))) short short8_t;
typedef __attribute__((ext_vector_type(4))) float float4_t;

__device__ __forceinline__ short f2bf(float f) {
    union { __hip_bfloat16 b; short s; } u;
    u.b = __float2bfloat16(f);
    return u.s;
}

// ---------------------------------------------------------------------------
// Kernel 1: dequantize packed 4-bit weights -> bf16 [N][K] (K-major)
// ---------------------------------------------------------------------------
__global__ __launch_bounds__(256) void dequant_w(const int* __restrict__ wd,
                                                 const float* __restrict__ scale,
                                                 const float* __restrict__ lut,
                                                 short* __restrict__ Wq) {
    int t = blockIdx.x * 256 + threadIdx.x;       // 2,097,152 threads total
    int row = t >> 9;                             // 512 threads per row
    int cb  = t & 511;                            // 4-byte chunk index within row
    const int4 w4 = *(const int4*)&wd[(size_t)row * 2048 + cb * 4];
    const float s = scale[row * 32 + (cb >> 4)];  // group = (8*cb)/128 = cb/16
    int idx[4] = {w4.x, w4.y, w4.z, w4.w};
    short8_t v;
#pragma unroll
    for (int j = 0; j < 4; ++j) {
        v[2 * j + 0] = f2bf(lut[idx[j] * 2 + 0] * s);
        v[2 * j + 1] = f2bf(lut[idx[j] * 2 + 1] * s);
    }
    *(short8_t*)&Wq[(size_t)row * K_DIM + cb * 8] = v;
}

// ---------------------------------------------------------------------------
// Kernel 2: x f32 -> bf16 (vectorized 8/thread)
// ---------------------------------------------------------------------------
__global__ __launch_bounds__(256) void conv_x(const float* __restrict__ x,
                                              short* __restrict__ xb) {
    size_t t = (size_t)blockIdx.x * 256 + threadIdx.x;  // 8,388,608 threads
    const float4 a = *(const float4*)(x + t * 8);
    const float4 b = *(const float4*)(x + t * 8 + 4);
    short8_t v;
    v[0] = f2bf(a.x); v[1] = f2bf(a.y); v[2] = f2bf(a.z); v[3] = f2bf(a.w);
    v[4] = f2bf(b.x); v[5] = f2bf(b.y); v[6] = f2bf(b.z); v[7] = f2bf(b.w);
    *(short8_t*)(xb + t * 8) = v;
}

// ---------------------------------------------------------------------------
// Kernel 3: 256x256 8-phase bf16 GEMM (T1+T2+T3+T4+T5), hoisted staging.
//   Staging schedule = round-3 (verified): slot s staged at phase s-5.
//   Each wave reads ONLY its own A/B half (wr/wc folded into base), so halves
//   are last-read at ph3 (A) / ph4 (B) for buf0, ph7/ph8 for buf1; stages
//   at those same phases are same-window-safe (ds_read issues before the
//   gload's LDS-write can land). vmcnt(4) at ph4/ph8 => only the current +
//   previous phase's stages may be outstanding => every read provably landed.
// ---------------------------------------------------------------------------
#define LOADA(MH, BUF) \
  _Pragma("unroll") for (int q = 0; q < 4; ++q) { \
    afr[q][0] = *(const short8_t*)(smem + ABASE + (BUF) + ((MH)*4+q)*1024); \
    afr[q][1] = *(const short8_t*)(smem + ABASE + (BUF) + 8192 + ((MH)*4+q)*1024); }

#define LOADB(NH, BUF) \
  _Pragma("unroll") for (int q = 0; q < 2; ++q) { \
    bfr[q][0] = *(const short8_t*)(smem + BBASE + (BUF) + ((NH)*2+q)*1024); \
    bfr[q][1] = *(const short8_t*)(smem + BBASE + (BUF) + 8192 + ((NH)*2+q)*1024); }

#define MFMAQ(MH, NH) \
  _Pragma("unroll") for (int q = 0; q < 4; ++q) \
  _Pragma("unroll") for (int p = 0; p < 2; ++p) { \
    acc[(MH)*4+q][(NH)*2+p] = __builtin_amdgcn_mfma_f32_16x16x32_bf16(afr[q][0], bfr[p][0], acc[(MH)*4+q][(NH)*2+p], 0, 0, 0); \
    acc[(MH)*4+q][(NH)*2+p] = __builtin_amdgcn_mfma_f32_16x16x32_bf16(afr[q][1], bfr[p][1], acc[(MH)*4+q][(NH)*2+p], 0, 0, 0); }

// one half-tile = 2 x global_load_lds dwordx4; P = per-thread src pointer,
// GOFF/DOFF compile-time literals
#define STAGE_F(P, GOFF, DOFF) \
  __builtin_amdgcn_global_load_lds((const __attribute__((address_space(1))) void*)((P) + (GOFF)), \
      (__attribute__((address_space(3))) void*)(smem + (DOFF) + f0), 16, 0, 0); \
  __builtin_amdgcn_global_load_lds((const __attribute__((address_space(1))) void*)((P) + (GOFF) + 64), \
      (__attribute__((address_space(3))) void*)(smem + (DOFF) + 8192 + f0), 16, 0, 0);

#define VM4 asm volatile("s_waitcnt vmcnt(4)" ::: "memory");
#define VM0 asm volatile("s_waitcnt vmcnt(0)" ::: "memory");

#define PH2(LOADS, MH, NH, STG, WAITV) \
    LOADS \
    STG \
    __builtin_amdgcn_s_barrier(); \
    asm volatile("s_waitcnt lgkmcnt(0)" ::: "memory"); \
    __builtin_amdgcn_s_setprio(1); \
    MFMAQ(MH, NH); \
    __builtin_amdgcn_s_setprio(0); \
    WAITV \
    __builtin_amdgcn_s_barrier();

// DOFF constants: (isB<<16) | (buf<<15) | (half<<14)
//   A0 b0=0      A1 b0=16384   A0 b1=32768   A1 b1=49152
//   B0 b0=65536  B1 b0=81920   B0 b1=98304   B1 b1=114688

__global__ __launch_bounds__(512, 2) void gemm8(const short* __restrict__ A,
                                                const short* __restrict__ B,
                                                float* __restrict__ C) {
    __shared__ __align__(16) char smem[131072];
    const int tid = threadIdx.x;
    const int lane = tid & 63;
    const int wid = tid >> 6;
    const int wr = wid >> 2, wc = wid & 3;
    const int lr = lane & 15;
    const int lk2 = ((lane >> 4) << 3) * 2;          // frag col byte {0,16,32,48}
    const int swz5 = ((lr >> 3) & 1) << 5;

    // T1: XCD-chunked bijective swizzle (grid 1024 = 8 XCDs x 128)
    int bid = ((blockIdx.x & 7) << 7) + (blockIdx.x >> 3);
    const int bm = bid >> 4, bn = bid & 15;          // 64 x 16 tiles

    // lane-constant LDS read bases (byte offsets); swizzle folded in
    const int ABASE = wr * 16384 + lr * 64 + (lk2 ^ swz5);
    const int BBASE = 65536 + (wc >> 1) * 16384 + (wc & 1) * 4096 + lr * 64 + (lk2 ^ swz5);

    // staging per-thread constants
    const int f0 = tid * 16;                          // LDS byte slot (linear dst)
    const int rr0 = tid >> 2;                         // staged row 0..127
    const int cs0 = (f0 & 63) ^ (((f0 >> 9) & 1) << 5);  // inverse-swz src col byte

    // persistent src pointers at K-tile 2t (advance 256 B/iter)
    const char* pA0 = (const char*)A + ((size_t)(bm * 256 + rr0) * K_DIM) * 2 + cs0;
    const char* pA1 = pA0 + (size_t)128 * K_DIM * 2;
    const char* pB0 = (const char*)B + ((size_t)(bn * 256 + rr0) * K_DIM) * 2 + cs0;
    const char* pB1 = pB0 + (size_t)128 * K_DIM * 2;

    float4_t acc[8][4] = {};
    short8_t afr[4][2], bfr[2][2];

    // prologue: kt0 {A0,B1,A1,B0} -> buf0, kt1 {A0,B1,A1,B0} -> buf1
    STAGE_F(pA0, 0,   0)
    STAGE_F(pB1, 0,   81920)
    STAGE_F(pA1, 0,   16384)
    STAGE_F(pB0, 0,   65536)
    STAGE_F(pA0, 128, 32768)
    STAGE_F(pB1, 128, 114688)
    STAGE_F(pA1, 128, 49152)
    STAGE_F(pB0, 128, 98304)
    asm volatile("s_waitcnt vmcnt(8)" ::: "memory");  // kt0 (buf0) landed
    __builtin_amdgcn_s_barrier();

    // iteration 0 (peeled): kt1 already fully staged; stages start at slot 8
    PH2(LOADA(0,0) LOADB(0,0), 0, 0, , )                                   // ph1
    PH2(LOADB(1,0),            0, 1, , )                                   // ph2
    PH2(LOADA(1,0),            1, 1, STAGE_F(pA0, 256, 0),      )          // ph3
    PH2(LOADB(0,0),            1, 0, STAGE_F(pB1, 256, 81920),  VM4)       // ph4
    PH2(LOADA(0,32768) LOADB(0,32768), 0, 0, STAGE_F(pA1, 256, 16384), )   // ph5
    PH2(LOADB(1,32768),                0, 1, STAGE_F(pB0, 256, 65536), )   // ph6
    PH2(LOADA(1,32768),                1, 1, STAGE_F(pA0, 384, 32768), )   // ph7
    PH2(LOADB(0,32768),                1, 0, STAGE_F(pB1, 384, 114688), VM4) // ph8
    pA0 += 256; pA1 += 256; pB0 += 256; pB1 += 256;

#pragma unroll 1
    for (int t = 1; t < 31; ++t) {
        // K-tile 2t from buf0; stage slot = phase + 5 (round-3 verified order)
        PH2(LOADA(0,0) LOADB(0,0), 0, 0, STAGE_F(pA1, 128, 49152),  )      // ph1: kt2t+1 A1->b1
        PH2(LOADB(1,0),            0, 1, STAGE_F(pB0, 128, 98304),  )      // ph2: kt2t+1 B0->b1
        PH2(LOADA(1,0),            1, 1, STAGE_F(pA0, 256, 0),      )      // ph3: kt2t+2 A0->b0
        PH2(LOADB(0,0),            1, 0, STAGE_F(pB1, 256, 81920),  VM4)   // ph4: kt2t+2 B1->b0
        // K-tile 2t+1 from buf1
        PH2(LOADA(0,32768) LOADB(0,32768), 0, 0, STAGE_F(pA1, 256, 16384), )   // ph5: kt2t+2 A1->b0
        PH2(LOADB(1,32768),                0, 1, STAGE_F(pB0, 256, 65536), )   // ph6: kt2t+2 B0->b0
        PH2(LOADA(1,32768),                1, 1, STAGE_F(pA0, 384, 32768), )   // ph7: kt2t+3 A0->b1
        PH2(LOADB(0,32768),                1, 0, STAGE_F(pB1, 384, 114688), VM4) // ph8: kt2t+3 B1->b1
        pA0 += 256; pA1 += 256; pB0 += 256; pB1 += 256;
    }

    // tail iteration t=31: only kt63 A1 (slot 254) and B0 (slot 255) remain
    PH2(LOADA(0,0) LOADB(0,0), 0, 0, STAGE_F(pA1, 128, 49152), )
    PH2(LOADB(1,0),            0, 1, STAGE_F(pB0, 128, 98304), )
    PH2(LOADA(1,0),            1, 1, , )
    PH2(LOADB(0,0),            1, 0, , VM0)
    PH2(LOADA(0,32768) LOADB(0,32768), 0, 0, , )
    PH2(LOADB(1,32768),                0, 1, , )
    PH2(LOADA(1,32768),                1, 1, , )
    PH2(LOADB(0,32768),                1, 0, , )

    // Epilogue: D mapping col = lane&15, row = (lane>>4)*4 + r (m89-verified)
    const int orow0 = bm * 256 + wr * 128;
    const int ocol0 = bn * 256 + wc * 64 + lr;
    const int rsub = (lane >> 4) << 2;
#pragma unroll
    for (int mi = 0; mi < 8; ++mi) {
#pragma unroll
        for (int r = 0; r < 4; ++r) {
            int row = orow0 + mi * 16 + rsub + r;
            float* cp = C + (size_t)row * N_DIM + ocol0;
#pragma unroll
            for (int ni = 0; ni < 4; ++ni)
                cp[ni * 16] = acc[mi][ni][r];
        }
    }
}

// ---------------------------------------------------------------------------
// Fallback GEMM (fp32 A staged with conversion) — only if workspace too small.
// ---------------------------------------------------------------------------
__global__ __launch_bounds__(256) void gemm_fb(const float* __restrict__ A,
                                               const short* __restrict__ B,
                                               float* __restrict__ C) {
    __shared__ short Al[128 * 32];
    __shared__ short Bl[128 * 32];
    const int bid0 = blockIdx.x;
    const int bid = (bid0 & 7) * 512 + (bid0 >> 3);
    const int bm = bid >> 5, bn = bid & 31;
    const int tid = threadIdx.x;
    const int lane = tid & 63;
    const int w = tid >> 6;
    const int wr = w >> 1, wc = w & 1;
    const int lr = lane & 15;
    const int lk = (lane >> 4) << 3;
    float4_t acc[4][4] = {};
    for (int k0 = 0; k0 < K_DIM; k0 += 32) {
        __syncthreads();
#pragma unroll
        for (int i = 0; i < 2; ++i) {
            int e = i * 2048 + tid * 8;
            int row = e >> 5, col = e & 31;
            const float* gp = A + (size_t)(bm * 128 + row) * K_DIM + k0 + col;
            float4 fa = *(const float4*)gp;
            float4 fb = *(const float4*)(gp + 4);
            short8_t v;
            v[0] = f2bf(fa.x); v[1] = f2bf(fa.y); v[2] = f2bf(fa.z); v[3] = f2bf(fa.w);
            v[4] = f2bf(fb.x); v[5] = f2bf(fb.y); v[6] = f2bf(fb.z); v[7] = f2bf(fb.w);
            *(short8_t*)&Al[e] = v;
        }
#pragma unroll
        for (int i = 0; i < 2; ++i) {
            int f = i * 4096 + tid * 16;
            int row = f >> 6, colb = f & 63;
            const char* gb = (const char*)B + ((size_t)(bn * 128 + row) * K_DIM + k0) * 2 + colb;
            __builtin_amdgcn_global_load_lds(
                (const __attribute__((address_space(1))) void*)gb,
                (__attribute__((address_space(3))) void*)((char*)Bl + f), 16, 0, 0);
        }
        __syncthreads();
        short8_t af[4], bf[4];
#pragma unroll
        for (int mi = 0; mi < 4; ++mi)
            af[mi] = *(const short8_t*)&Al[(wr * 64 + mi * 16 + lr) * 32 + lk];
#pragma unroll
        for (int ni = 0; ni < 4; ++ni)
            bf[ni] = *(const short8_t*)&Bl[(wc * 64 + ni * 16 + lr) * 32 + lk];
#pragma unroll
        for (int mi = 0; mi < 4; ++mi)
#pragma unroll
            for (int ni = 0; ni < 4; ++ni)
                acc[mi][ni] = __builtin_amdgcn_mfma_f32_16x16x32_bf16(af[mi], bf[ni], acc[mi][ni], 0, 0, 0);
    }
    const int orow0 = bm * 128 + wr * 64;
    const int ocol0 = bn * 128 + wc * 64 + (lane & 15);
#pragma unroll
    for (int mi = 0; mi < 4; ++mi)
#pragma unroll
        for (int r = 0; r < 4; ++r) {
            int row = orow0 + mi * 16 + ((lane >> 4) << 2) + r;
            float* cp = C + (size_t)row * N_DIM + ocol0;
#pragma unroll
            for (int ni = 0; ni < 4; ++ni)
                cp[ni * 16] = acc[mi][ni][r];
        }
}

// ---------------------------------------------------------------------------
extern "C" void kernel_launch(void* const* d_in, const int* in_sizes, int n_in,
                              void* d_out, int out_size, void* d_ws, size_t ws_size,
                              hipStream_t stream) {
    const float* x     = (const float*)d_in[0];
    const int*   wd    = (const int*)d_in[1];
    const float* scale = (const float*)d_in[2];
    const float* lut   = (const float*)d_in[3];
    float* out = (float*)d_out;

    const size_t wq_bytes = (size_t)N_DIM * K_DIM * 2;   // 32 MB
    const size_t xb_bytes = (size_t)M_DIM * K_DIM * 2;   // 128 MB
    short* Wq = (short*)d_ws;
    short* xb = (short*)((char*)d_ws + wq_bytes);
    const bool have_xb = ws_size >= wq_bytes + xb_bytes;

    dequant_w<<<8192, 256, 0, stream>>>(wd, scale, lut, Wq);

    if (have_xb) {
        conv_x<<<32768, 256, 0, stream>>>(x, xb);
        gemm8<<<(M_DIM / 256) * (N_DIM / 256), 512, 0, stream>>>(xb, Wq, out);
    } else {
        gemm_fb<<<(M_DIM / 128) * (N_DIM / 128), 256, 0, stream>>>(x, Wq, out);
    }
}